// Round 3
// baseline (2726.855 us; speedup 1.0000x reference)
//
#include <hip/hip_runtime.h>
#include <hip/hip_bf16.h>
#include <hip/hip_cooperative_groups.h>
#include <cstddef>

namespace cg = cooperative_groups;

// WITRAN 2D PSGMU encoder, MI355X — persistent cooperative kernel.
// B=32, rows=48, cols(R)=24, C=32, H=256, L=71, N=768, K=544, Ngate=1536.
// Split-W (hi+lo bf16) MFMA 16x16x32; W held in VGPRs for all 71 steps.
// Grid 256 = 16 m-chunks (48 rows) x 16 k-tiles (16 hidden dims x 6 gates).
// Block 384 thr = 6 waves, wave wv = gate group g; grid.sync() between steps.

namespace {
constexpr int H_   = 256;
constexpr int C_   = 32;
constexpr int B_   = 32;
constexpr int R_   = 24;
constexpr int LOR_ = 48;
constexpr int L_   = 71;
constexpr int N_   = 768;
constexpr int KH_  = 512;
constexpr int KT_  = 544;
constexpr int AST_ = 552;   // LDS A stride (elems): 552*2B=1104B -> 2-way banks
}

typedef __attribute__((ext_vector_type(8))) __bf16 bf16x8;
typedef __attribute__((ext_vector_type(4))) float  f32x4;
typedef __attribute__((ext_vector_type(2))) float  f32x2;

__device__ __forceinline__ float fsig(float x)  { return 1.f / (1.f + __expf(-x)); }
__device__ __forceinline__ float ftanhf(float x){ float e = __expf(2.f * x); return 1.f - 2.f / (e + 1.f); }

// ---------------------------------------------------------------------------
// Prep 1: W -> fragment-native split-bf16 (same layout as v1, verified).
// Wfrag[(((pass*17+kc)*96 + lt)*64 + lane)*8 + j8]; lt=kt*6+g; col j=g*256+kt*16+kl
// ---------------------------------------------------------------------------
__global__ __launch_bounds__(256) void prep_w(const float* __restrict__ W,
                                              __hip_bfloat16* __restrict__ Wfrag) {
    int o = blockIdx.x * 256 + threadIdx.x;          // < 1,671,168
    int j8   = o & 7;
    int lane = (o >> 3) & 63;
    int rest = o >> 9;
    int lt    = rest % 96;
    int rest2 = rest / 96;
    int kc   = rest2 % 17;
    int pass = rest2 / 17;
    int n0 = lane & 15, quad = lane >> 4;
    int lg  = lt * 16 + n0;
    int kt  = lg / 96;
    int rem = lg % 96;
    int g  = rem >> 4, kl = rem & 15;
    int j  = g * 256 + kt * 16 + kl;
    int kg = kc * 32 + quad * 8 + j8;
    float w = W[j * KT_ + kg];
    __hip_bfloat16 hi = __float2bfloat16(w);
    if (pass) { w = w - __bfloat162float(hi); hi = __float2bfloat16(w); }
    Wfrag[o] = hi;
}

// ---------------------------------------------------------------------------
// Prep 2: all shifted x slices, bf16. xall[s][n][c], n=r*32+b, l=s-r.
// ---------------------------------------------------------------------------
__global__ __launch_bounds__(256) void prep_x(const float* __restrict__ inp,
                                              __hip_bfloat16* __restrict__ xall) {
    int o = blockIdx.x * 256 + threadIdx.x;          // < 1,744,896
    int c = o & 31;
    int n = (o >> 5) % N_;
    int s = (o >> 5) / N_;
    int r = n >> 5, b = n & 31;
    int l = s - r;
    float v = 0.f;
    if (l >= 0 && l < LOR_) v = inp[((b * LOR_ + l) * R_ + r) * C_ + c];
    xall[o] = __float2bfloat16(v);
}

// ---------------------------------------------------------------------------
// Persistent step kernel.
// ---------------------------------------------------------------------------
__global__ __launch_bounds__(384, 2) void persist_k(
    const __hip_bfloat16* __restrict__ Wfrag,
    const __hip_bfloat16* __restrict__ xall,
    __hip_bfloat16* __restrict__ hbf0, __hip_bfloat16* __restrict__ hbf1,
    float* __restrict__ hf0, float* __restrict__ hf1,
    const float* __restrict__ Bp,
    float* __restrict__ out0, float* __restrict__ out1, float* __restrict__ out2)
{
    cg::grid_group grid = cg::this_grid();

    __shared__ unsigned short As[48 * AST_];   // A tile: 48 rows x 544 (pad 552)
    __shared__ float Gt[48][104];              // gate tile 48m x 96l

    const int t    = threadIdx.x;
    const int wv   = t >> 6;                   // 0..5 = gate group g
    const int lane = t & 63;
    const int n0   = lane & 15;
    const int quad = lane >> 4;
    const int kt   = blockIdx.x & 15;
    const int mc   = blockIdx.x >> 4;          // 0..15, rows [mc*48, mc*48+48)

    // ---- load this wave's W slab into registers, once -----------------------
    bf16x8 bw[34];                             // [kc*2 + pass]
#pragma unroll
    for (int kc = 0; kc < 17; ++kc) {
#pragma unroll
        for (int p = 0; p < 2; ++p) {
            bw[kc * 2 + p] = *(const bf16x8*)(const void*)(
                Wfrag + ((size_t)((p * 17 + kc) * 96 + kt * 6 + wv) * 64 + lane) * 8);
        }
    }

    for (int s = 0; s < L_; ++s) {
        const __hip_bfloat16* hbc = (s & 1) ? hbf1 : hbf0;
        __hip_bfloat16*       hbn = (s & 1) ? hbf0 : hbf1;
        const float*          hfc = (s & 1) ? hf1 : hf0;
        float*                hfn = (s & 1) ? hf0 : hf1;

        // ---- stage A (h 48x512 + x 48x32) into LDS --------------------------
#pragma unroll
        for (int it = 0; it < 8; ++it) {
            int q   = it * 384 + t;            // < 3072
            int row = q >> 6;
            int col = (q & 63) * 8;
            *(bf16x8*)(void*)(&As[row * AST_ + col]) =
                *(const bf16x8*)(const void*)(hbc + (size_t)(mc * 48 + row) * KH_ + col);
        }
        if (t < 192) {
            int row = t >> 2;
            int col = (t & 3) * 8;
            *(bf16x8*)(void*)(&As[row * AST_ + 512 + col]) =
                *(const bf16x8*)(const void*)(xall + (size_t)(s * N_ + mc * 48 + row) * C_ + col);
        }
        __syncthreads();

        // ---- GEMM: wave = gate g, 3 m-tiles x 16 gate cols ------------------
        f32x4 acc[3];
#pragma unroll
        for (int mt = 0; mt < 3; ++mt) acc[mt] = (f32x4){0.f, 0.f, 0.f, 0.f};

#pragma unroll
        for (int kc = 0; kc < 17; ++kc) {
            bf16x8 a[3];
#pragma unroll
            for (int mt = 0; mt < 3; ++mt)
                a[mt] = *(const bf16x8*)(const void*)(
                    &As[(mt * 16 + n0) * AST_ + kc * 32 + quad * 8]);
#pragma unroll
            for (int mt = 0; mt < 3; ++mt) {
                acc[mt] = __builtin_amdgcn_mfma_f32_16x16x32_bf16(a[mt], bw[kc * 2 + 0], acc[mt], 0, 0, 0);
                acc[mt] = __builtin_amdgcn_mfma_f32_16x16x32_bf16(a[mt], bw[kc * 2 + 1], acc[mt], 0, 0, 0);
            }
        }

        // D layout: col = lane&15 (gate col), row = quad*4 + reg (m)
#pragma unroll
        for (int mt = 0; mt < 3; ++mt)
#pragma unroll
            for (int reg = 0; reg < 4; ++reg)
                Gt[mt * 16 + quad * 4 + reg][wv * 16 + n0] = acc[mt][reg];

        __syncthreads();

        // ---- fused update: 48m x 16k, thread = 1 m-row x 2 k ----------------
        {
            const int mm = t >> 3;
            const int kp = (t & 7) * 2;
            const int n  = mc * 48 + mm;
            const int k  = kt * 16 + kp;
            const int r  = n >> 5, b = n & 31;
            const bool useb = (r <= s) && (s < R_);

            f32x2 gv[6];
#pragma unroll
            for (int g = 0; g < 6; ++g) {
                f32x2 v  = *(const f32x2*)(const void*)&Gt[mm][g * 16 + kp];
                f32x2 bp = *(const f32x2*)(const void*)(Bp + g * 256 + k);
                gv[g] = useb ? (v + bp) : v;
            }

            f32x2 hro = *(const f32x2*)(const void*)(hfc + (size_t)n * KH_ + k);
            f32x2 hco = *(const f32x2*)(const void*)(hfc + (size_t)n * KH_ + 256 + k);

            f32x2 hrv, hcv;
#pragma unroll
            for (int j = 0; j < 2; ++j) {
                float ur = fsig(gv[0][j]);
                float oR = fsig(gv[1][j]);
                float uc = fsig(gv[2][j]);
                float oc = fsig(gv[3][j]);
                float ir = ftanhf(gv[4][j]);
                float ic = ftanhf(gv[5][j]);
                hrv[j] = ftanhf((1.f - ur) * hro[j] + ur * ir) * oR;
                hcv[j] = ftanhf((1.f - uc) * hco[j] + uc * ic) * oc;
            }

            float* o0 = out0 + ((size_t)n * L_ + s) * 512;
            *(f32x2*)(void*)(o0 + k)       = hrv;
            *(f32x2*)(void*)(o0 + 256 + k) = hcv;

            int n2 = n + B_; if (n2 >= N_) n2 -= N_;
            *(f32x2*)(void*)(hfn + (size_t)n  * KH_ + k)       = hrv;
            *(f32x2*)(void*)(hfn + (size_t)n2 * KH_ + 256 + k) = hcv;

            __hip_bfloat162 hr2, hc2;
            hr2.x = __float2bfloat16(hrv[0]); hr2.y = __float2bfloat16(hrv[1]);
            hc2.x = __float2bfloat16(hcv[0]); hc2.y = __float2bfloat16(hcv[1]);
            *(__hip_bfloat162*)(void*)(hbn + (size_t)n  * KH_ + k)       = hr2;
            *(__hip_bfloat162*)(void*)(hbn + (size_t)n2 * KH_ + 256 + k) = hc2;

            if (s >= LOR_ - 1 && r == s - (LOR_ - 1))
                *(f32x2*)(void*)(out2 + (size_t)(b * R_ + r) * H_ + k) = hrv;
            if (r == R_ - 1 && s >= R_ - 1)
                *(f32x2*)(void*)(out1 + (size_t)(b * LOR_ + (s - (R_ - 1))) * H_ + k) = hcv;
        }

        grid.sync();
    }
}

// ---------------------------------------------------------------------------
extern "C" void kernel_launch(void* const* d_in, const int* in_sizes, int n_in,
                              void* d_out, int out_size, void* d_ws, size_t ws_size,
                              hipStream_t stream) {
    const float* inp = (const float*)d_in[0];
    const float* W   = (const float*)d_in[1];
    const float* Bp  = (const float*)d_in[2];

    float* out0 = (float*)d_out;
    float* out1 = out0 + (size_t)N_ * L_ * 512;
    float* out2 = out1 + (size_t)B_ * LOR_ * H_;

    char* ws = (char*)d_ws;
    __hip_bfloat16* Wfrag = (__hip_bfloat16*)(ws);                 // 3,342,336 B
    __hip_bfloat16* xall  = (__hip_bfloat16*)(ws + 3342336);       // 3,489,792 B
    __hip_bfloat16* hbf0  = (__hip_bfloat16*)(ws + 6832128);       //   786,432 B
    __hip_bfloat16* hbf1  = (__hip_bfloat16*)(ws + 7618560);       //   786,432 B
    float*          hf0   = (float*)(ws + 8404992);                // 1,572,864 B
    float*          hf1   = (float*)(ws + 9977856);                // 1,572,864 B

    (void)hipMemsetAsync(hbf0, 0, 786432, stream);
    (void)hipMemsetAsync(hf0,  0, 1572864, stream);

    prep_w<<<6528, 256, 0, stream>>>(W, Wfrag);
    prep_x<<<6816, 256, 0, stream>>>(inp, xall);

    void* args[] = { (void*)&Wfrag, (void*)&xall, (void*)&hbf0, (void*)&hbf1,
                     (void*)&hf0, (void*)&hf1, (void*)&Bp,
                     (void*)&out0, (void*)&out1, (void*)&out2 };
    (void)hipLaunchCooperativeKernel((void*)persist_k, dim3(256), dim3(384),
                                     args, 0, stream);
}

// Round 4
// 2162.338 us; speedup vs baseline: 1.2611x; 1.2611x over previous
//
#include <hip/hip_runtime.h>
#include <hip/hip_bf16.h>
#include <cstddef>

// WITRAN 2D PSGMU encoder, MI355X — persistent kernel, custom grid barrier.
// B=32, rows=48, cols(R)=24, C=32, H=256, L=71, N=768, K=544, Ngate=1536.
// Split-W (hi+lo bf16) MFMA 16x16x32. Grid 256 = 16 m-chunks x 16 k-tiles.
// Block 384 thr = 6 waves (wave = gate group). Custom barrier: __threadfence
// (agent acq/rel, same semantics grid.sync used — verified correct in R3) +
// one monotonic agent-scope counter; no s_sleep-based cg::grid.sync.

namespace {
constexpr int H_   = 256;
constexpr int C_   = 32;
constexpr int B_   = 32;
constexpr int R_   = 24;
constexpr int LOR_ = 48;
constexpr int L_   = 71;
constexpr int N_   = 768;
constexpr int KH_  = 512;
constexpr int KT_  = 544;
constexpr int AST_ = 552;   // LDS A stride (elems)
constexpr int NBLK_= 256;
}

typedef __attribute__((ext_vector_type(8))) __bf16 bf16x8;
typedef __attribute__((ext_vector_type(4))) float  f32x4;
typedef __attribute__((ext_vector_type(2))) float  f32x2;

__device__ __forceinline__ float fsig(float x)  { return 1.f / (1.f + __expf(-x)); }
__device__ __forceinline__ float ftanhf(float x){ float e = __expf(2.f * x); return 1.f - 2.f / (e + 1.f); }

// ---------------------------------------------------------------------------
__global__ __launch_bounds__(256) void prep_w(const float* __restrict__ W,
                                              __hip_bfloat16* __restrict__ Wfrag) {
    int o = blockIdx.x * 256 + threadIdx.x;          // < 1,671,168
    int j8   = o & 7;
    int lane = (o >> 3) & 63;
    int rest = o >> 9;
    int lt    = rest % 96;
    int rest2 = rest / 96;
    int kc   = rest2 % 17;
    int pass = rest2 / 17;
    int n0 = lane & 15, quad = lane >> 4;
    int lg  = lt * 16 + n0;
    int kt  = lg / 96;
    int rem = lg % 96;
    int g  = rem >> 4, kl = rem & 15;
    int j  = g * 256 + kt * 16 + kl;
    int kg = kc * 32 + quad * 8 + j8;
    float w = W[j * KT_ + kg];
    __hip_bfloat16 hi = __float2bfloat16(w);
    if (pass) { w = w - __bfloat162float(hi); hi = __float2bfloat16(w); }
    Wfrag[o] = hi;
}

// ---------------------------------------------------------------------------
__global__ __launch_bounds__(256) void prep_x(const float* __restrict__ inp,
                                              __hip_bfloat16* __restrict__ xall) {
    int o = blockIdx.x * 256 + threadIdx.x;          // < 1,744,896
    int c = o & 31;
    int n = (o >> 5) % N_;
    int s = (o >> 5) / N_;
    int r = n >> 5, b = n & 31;
    int l = s - r;
    float v = 0.f;
    if (l >= 0 && l < LOR_) v = inp[((b * LOR_ + l) * R_ + r) * C_ + c];
    xall[o] = __float2bfloat16(v);
}

// ---------------------------------------------------------------------------
// Custom grid barrier: monotonic counter, agent scope. Caller passes step.
// Semantics match grid.sync(): release (threadfence) -> arrive -> spin ->
// acquire (threadfence) -> block barrier.
// ---------------------------------------------------------------------------
__device__ __forceinline__ void grid_bar(unsigned int* cnt, int step) {
    __syncthreads();                       // all waves' stores vmcnt-drained
    if (threadIdx.x == 0) {
        __threadfence();                   // wbl2: this XCD's dirty lines out
        __hip_atomic_fetch_add(cnt, 1u, __ATOMIC_RELAXED, __HIP_MEMORY_SCOPE_AGENT);
        const unsigned int target = (unsigned int)NBLK_ * (unsigned int)(step + 1);
        while (__hip_atomic_load(cnt, __ATOMIC_RELAXED, __HIP_MEMORY_SCOPE_AGENT) < target) {
            __builtin_amdgcn_s_sleep(1);
        }
        __threadfence();                   // inv: fresh reads next step
    }
    __syncthreads();
}

// ---------------------------------------------------------------------------
__global__ __launch_bounds__(384, 2) void persist_k(
    const __hip_bfloat16* __restrict__ Wfrag,
    const __hip_bfloat16* __restrict__ xall,
    __hip_bfloat16* __restrict__ hbf0, __hip_bfloat16* __restrict__ hbf1,
    float* __restrict__ hf0, float* __restrict__ hf1,
    const float* __restrict__ Bp,
    float* __restrict__ out0, float* __restrict__ out1, float* __restrict__ out2,
    unsigned int* __restrict__ cnt)
{
    __shared__ unsigned short As[48 * AST_];   // A tile: 48 rows x 544 (pad 552)
    __shared__ float Gt[48][104];              // gate tile 48m x 96l

    const int t    = threadIdx.x;
    const int wv   = t >> 6;                   // 0..5 = gate group g
    const int lane = t & 63;
    const int n0   = lane & 15;
    const int quad = lane >> 4;
    const int kt   = blockIdx.x & 15;
    const int mc   = blockIdx.x >> 4;          // rows [mc*48, mc*48+48)

    for (int s = 0; s < L_; ++s) {
        const __hip_bfloat16* hbc = (s & 1) ? hbf1 : hbf0;
        __hip_bfloat16*       hbn = (s & 1) ? hbf0 : hbf1;
        const float*          hfc = (s & 1) ? hf1 : hf0;
        float*                hfn = (s & 1) ? hf0 : hf1;

        // ---- stage A (h 48x512 + x 48x32) into LDS --------------------------
#pragma unroll
        for (int it = 0; it < 8; ++it) {
            int q   = it * 384 + t;            // < 3072
            int row = q >> 6;
            int col = (q & 63) * 8;
            *(bf16x8*)(void*)(&As[row * AST_ + col]) =
                *(const bf16x8*)(const void*)(hbc + (size_t)(mc * 48 + row) * KH_ + col);
        }
        if (t < 192) {
            int row = t >> 2;
            int col = (t & 3) * 8;
            *(bf16x8*)(void*)(&As[row * AST_ + 512 + col]) =
                *(const bf16x8*)(const void*)(xall + (size_t)(s * N_ + mc * 48 + row) * C_ + col);
        }
        __syncthreads();

        // ---- GEMM: wave = gate g, 3 m-tiles x 16 gate cols ------------------
        f32x4 acc[3];
#pragma unroll
        for (int mt = 0; mt < 3; ++mt) acc[mt] = (f32x4){0.f, 0.f, 0.f, 0.f};

#pragma unroll
        for (int kc = 0; kc < 17; ++kc) {
            bf16x8 bhi = *(const bf16x8*)(const void*)(
                Wfrag + ((size_t)((kc)*96 + kt * 6 + wv) * 64 + lane) * 8);
            bf16x8 blo = *(const bf16x8*)(const void*)(
                Wfrag + ((size_t)((17 + kc) * 96 + kt * 6 + wv) * 64 + lane) * 8);
            bf16x8 a[3];
#pragma unroll
            for (int mt = 0; mt < 3; ++mt)
                a[mt] = *(const bf16x8*)(const void*)(
                    &As[(mt * 16 + n0) * AST_ + kc * 32 + quad * 8]);
#pragma unroll
            for (int mt = 0; mt < 3; ++mt) {
                acc[mt] = __builtin_amdgcn_mfma_f32_16x16x32_bf16(a[mt], bhi, acc[mt], 0, 0, 0);
                acc[mt] = __builtin_amdgcn_mfma_f32_16x16x32_bf16(a[mt], blo, acc[mt], 0, 0, 0);
            }
        }

        // D layout: col = lane&15 (gate col), row = quad*4 + reg (m)
#pragma unroll
        for (int mt = 0; mt < 3; ++mt)
#pragma unroll
            for (int reg = 0; reg < 4; ++reg)
                Gt[mt * 16 + quad * 4 + reg][wv * 16 + n0] = acc[mt][reg];

        __syncthreads();

        // ---- fused update: 48m x 16k, thread = 1 m-row x 2 k ----------------
        {
            const int mm = t >> 3;
            const int kp = (t & 7) * 2;
            const int n  = mc * 48 + mm;
            const int k  = kt * 16 + kp;
            const int r  = n >> 5, b = n & 31;
            const bool useb = (r <= s) && (s < R_);

            f32x2 gv[6];
#pragma unroll
            for (int g = 0; g < 6; ++g) {
                f32x2 v  = *(const f32x2*)(const void*)&Gt[mm][g * 16 + kp];
                f32x2 bp = *(const f32x2*)(const void*)(Bp + g * 256 + k);
                gv[g] = useb ? (v + bp) : v;
            }

            f32x2 hro = *(const f32x2*)(const void*)(hfc + (size_t)n * KH_ + k);
            f32x2 hco = *(const f32x2*)(const void*)(hfc + (size_t)n * KH_ + 256 + k);

            f32x2 hrv, hcv;
#pragma unroll
            for (int j = 0; j < 2; ++j) {
                float ur = fsig(gv[0][j]);
                float oR = fsig(gv[1][j]);
                float uc = fsig(gv[2][j]);
                float oc = fsig(gv[3][j]);
                float ir = ftanhf(gv[4][j]);
                float ic = ftanhf(gv[5][j]);
                hrv[j] = ftanhf((1.f - ur) * hro[j] + ur * ir) * oR;
                hcv[j] = ftanhf((1.f - uc) * hco[j] + uc * ic) * oc;
            }

            // trace output (write-only: non-temporal, keep L2 clean)
            float* o0 = out0 + ((size_t)n * L_ + s) * 512;
            __builtin_nontemporal_store(hrv, (f32x2*)(void*)(o0 + k));
            __builtin_nontemporal_store(hcv, (f32x2*)(void*)(o0 + 256 + k));

            int n2 = n + B_; if (n2 >= N_) n2 -= N_;
            *(f32x2*)(void*)(hfn + (size_t)n  * KH_ + k)       = hrv;
            *(f32x2*)(void*)(hfn + (size_t)n2 * KH_ + 256 + k) = hcv;

            __hip_bfloat162 hr2, hc2;
            hr2.x = __float2bfloat16(hrv[0]); hr2.y = __float2bfloat16(hrv[1]);
            hc2.x = __float2bfloat16(hcv[0]); hc2.y = __float2bfloat16(hcv[1]);
            *(__hip_bfloat162*)(void*)(hbn + (size_t)n  * KH_ + k)       = hr2;
            *(__hip_bfloat162*)(void*)(hbn + (size_t)n2 * KH_ + 256 + k) = hc2;

            if (s >= LOR_ - 1 && r == s - (LOR_ - 1))
                __builtin_nontemporal_store(hrv, (f32x2*)(void*)(out2 + (size_t)(b * R_ + r) * H_ + k));
            if (r == R_ - 1 && s >= R_ - 1)
                __builtin_nontemporal_store(hcv, (f32x2*)(void*)(out1 + (size_t)(b * LOR_ + (s - (R_ - 1))) * H_ + k));
        }

        if (s < L_ - 1) grid_bar(cnt, s);
    }
}

// ---------------------------------------------------------------------------
extern "C" void kernel_launch(void* const* d_in, const int* in_sizes, int n_in,
                              void* d_out, int out_size, void* d_ws, size_t ws_size,
                              hipStream_t stream) {
    const float* inp = (const float*)d_in[0];
    const float* W   = (const float*)d_in[1];
    const float* Bp  = (const float*)d_in[2];

    float* out0 = (float*)d_out;
    float* out1 = out0 + (size_t)N_ * L_ * 512;
    float* out2 = out1 + (size_t)B_ * LOR_ * H_;

    char* ws = (char*)d_ws;
    __hip_bfloat16* Wfrag = (__hip_bfloat16*)(ws);                 // 3,342,336 B
    __hip_bfloat16* xall  = (__hip_bfloat16*)(ws + 3342336);       // 3,489,792 B
    __hip_bfloat16* hbf0  = (__hip_bfloat16*)(ws + 6832128);       //   786,432 B
    __hip_bfloat16* hbf1  = (__hip_bfloat16*)(ws + 7618560);       //   786,432 B
    float*          hf0   = (float*)(ws + 8404992);                // 1,572,864 B
    float*          hf1   = (float*)(ws + 9977856);                // 1,572,864 B
    unsigned int*   cnt   = (unsigned int*)(ws + 11550720);        //         4 B

    (void)hipMemsetAsync(hbf0, 0, 786432, stream);
    (void)hipMemsetAsync(hf0,  0, 1572864, stream);
    (void)hipMemsetAsync(cnt,  0, 4, stream);

    prep_w<<<6528, 256, 0, stream>>>(W, Wfrag);
    prep_x<<<6816, 256, 0, stream>>>(inp, xall);

    void* args[] = { (void*)&Wfrag, (void*)&xall, (void*)&hbf0, (void*)&hbf1,
                     (void*)&hf0, (void*)&hf1, (void*)&Bp,
                     (void*)&out0, (void*)&out1, (void*)&out2, (void*)&cnt };
    (void)hipLaunchCooperativeKernel((void*)persist_k, dim3(NBLK_), dim3(384),
                                     args, 0, stream);
}

// Round 5
// 760.075 us; speedup vs baseline: 3.5876x; 2.8449x over previous
//
#include <hip/hip_runtime.h>
#include <hip/hip_bf16.h>
#include <cstddef>

// WITRAN 2D PSGMU encoder, MI355X — v4: back to launch-per-step (CP is the
// fastest barrier: v1 17us/step vs software grid barriers 30-38us/step),
// with the lean v3 step structure: 256 blocks = 16 m-chunks x 16 k-tiles,
// 384 thr = 6 waves, wave = gate group (204 KB W/block/step, 4x less than v1).
// Split-W (hi+lo bf16) MFMA 16x16x32, fp32 h carry + bf16 shadow (verified).

namespace {
constexpr int H_   = 256;
constexpr int C_   = 32;
constexpr int B_   = 32;
constexpr int R_   = 24;
constexpr int LOR_ = 48;
constexpr int L_   = 71;
constexpr int N_   = 768;
constexpr int KH_  = 512;
constexpr int KT_  = 544;
constexpr int AST_ = 552;   // LDS A stride (elems)
}

typedef __attribute__((ext_vector_type(8))) __bf16 bf16x8;
typedef __attribute__((ext_vector_type(4))) float  f32x4;
typedef __attribute__((ext_vector_type(2))) float  f32x2;

__device__ __forceinline__ float fsig(float x)  { return 1.f / (1.f + __expf(-x)); }
__device__ __forceinline__ float ftanhf(float x){ float e = __expf(2.f * x); return 1.f - 2.f / (e + 1.f); }

// ---------------------------------------------------------------------------
// Prep 1: W -> fragment-native split-bf16 (layout verified in v1/v3).
// Wfrag[(((pass*17+kc)*96 + lt)*64 + lane)*8 + j8]; lt=kt*6+g; col j=g*256+kt*16+kl
// ---------------------------------------------------------------------------
__global__ __launch_bounds__(256) void prep_w(const float* __restrict__ W,
                                              __hip_bfloat16* __restrict__ Wfrag) {
    int o = blockIdx.x * 256 + threadIdx.x;          // < 1,671,168
    int j8   = o & 7;
    int lane = (o >> 3) & 63;
    int rest = o >> 9;
    int lt    = rest % 96;
    int rest2 = rest / 96;
    int kc   = rest2 % 17;
    int pass = rest2 / 17;
    int n0 = lane & 15, quad = lane >> 4;
    int lg  = lt * 16 + n0;
    int kt  = lg / 96;
    int rem = lg % 96;
    int g  = rem >> 4, kl = rem & 15;
    int j  = g * 256 + kt * 16 + kl;
    int kg = kc * 32 + quad * 8 + j8;
    float w = W[j * KT_ + kg];
    __hip_bfloat16 hi = __float2bfloat16(w);
    if (pass) { w = w - __bfloat162float(hi); hi = __float2bfloat16(w); }
    Wfrag[o] = hi;
}

// ---------------------------------------------------------------------------
// Prep 2: all shifted x slices, bf16. xall[s][n][c], n=r*32+b, l=s-r.
// ---------------------------------------------------------------------------
__global__ __launch_bounds__(256) void prep_x(const float* __restrict__ inp,
                                              __hip_bfloat16* __restrict__ xall) {
    int o = blockIdx.x * 256 + threadIdx.x;          // < 1,744,896
    int c = o & 31;
    int n = (o >> 5) % N_;
    int s = (o >> 5) / N_;
    int r = n >> 5, b = n & 31;
    int l = s - r;
    float v = 0.f;
    if (l >= 0 && l < LOR_) v = inp[((b * LOR_ + l) * R_ + r) * C_ + c];
    xall[o] = __float2bfloat16(v);
}

// ---------------------------------------------------------------------------
// One step. 256 blocks: kt = bx&15, mc = bx>>4 (rows [mc*48, mc*48+48)).
// 6 waves, wave wv = gate group g.
// ---------------------------------------------------------------------------
__global__ __launch_bounds__(384, 2) void step_k(
    const __hip_bfloat16* __restrict__ Wfrag,
    const __hip_bfloat16* __restrict__ xall,
    const __hip_bfloat16* __restrict__ hbc,
    const float*          __restrict__ hfc,
    __hip_bfloat16*       __restrict__ hbn,
    float*                __restrict__ hfn,
    const float* __restrict__ Bp,
    float* __restrict__ out0, float* __restrict__ out1, float* __restrict__ out2,
    int s)
{
    __shared__ unsigned short As[48 * AST_];   // A tile: 48 rows x 544 (pad 552)
    __shared__ float Gt[48][104];              // gate tile 48m x 96l

    const int t    = threadIdx.x;
    const int wv   = t >> 6;                   // 0..5 = gate group g
    const int lane = t & 63;
    const int n0   = lane & 15;
    const int quad = lane >> 4;
    const int kt   = blockIdx.x & 15;
    const int mc   = blockIdx.x >> 4;

    // ---- stage A (h 48x512 + x 48x32) into LDS ------------------------------
#pragma unroll
    for (int it = 0; it < 8; ++it) {
        int q   = it * 384 + t;                // < 3072
        int row = q >> 6;
        int col = (q & 63) * 8;
        *(bf16x8*)(void*)(&As[row * AST_ + col]) =
            *(const bf16x8*)(const void*)(hbc + (size_t)(mc * 48 + row) * KH_ + col);
    }
    if (t < 192) {
        int row = t >> 2;
        int col = (t & 3) * 8;
        *(bf16x8*)(void*)(&As[row * AST_ + 512 + col]) =
            *(const bf16x8*)(const void*)(xall + (size_t)(s * N_ + mc * 48 + row) * C_ + col);
    }
    __syncthreads();

    // ---- GEMM: wave = gate g, 3 m-tiles x 16 gate cols ----------------------
    f32x4 acc[3];
#pragma unroll
    for (int mt = 0; mt < 3; ++mt) acc[mt] = (f32x4){0.f, 0.f, 0.f, 0.f};

#pragma unroll
    for (int kc = 0; kc < 17; ++kc) {
        bf16x8 bhi = *(const bf16x8*)(const void*)(
            Wfrag + ((size_t)((kc)*96 + kt * 6 + wv) * 64 + lane) * 8);
        bf16x8 blo = *(const bf16x8*)(const void*)(
            Wfrag + ((size_t)((17 + kc) * 96 + kt * 6 + wv) * 64 + lane) * 8);
        bf16x8 a[3];
#pragma unroll
        for (int mt = 0; mt < 3; ++mt)
            a[mt] = *(const bf16x8*)(const void*)(
                &As[(mt * 16 + n0) * AST_ + kc * 32 + quad * 8]);
#pragma unroll
        for (int mt = 0; mt < 3; ++mt) {
            acc[mt] = __builtin_amdgcn_mfma_f32_16x16x32_bf16(a[mt], bhi, acc[mt], 0, 0, 0);
            acc[mt] = __builtin_amdgcn_mfma_f32_16x16x32_bf16(a[mt], blo, acc[mt], 0, 0, 0);
        }
    }

    // D layout: col = lane&15 (gate col), row = quad*4 + reg (m)
#pragma unroll
    for (int mt = 0; mt < 3; ++mt)
#pragma unroll
        for (int reg = 0; reg < 4; ++reg)
            Gt[mt * 16 + quad * 4 + reg][wv * 16 + n0] = acc[mt][reg];

    __syncthreads();

    // ---- fused update: 48m x 16k, thread = 1 m-row x 2 k --------------------
    {
        const int mm = t >> 3;
        const int kp = (t & 7) * 2;
        const int n  = mc * 48 + mm;
        const int k  = kt * 16 + kp;
        const int r  = n >> 5, b = n & 31;
        const bool useb = (r <= s) && (s < R_);

        f32x2 gv[6];
#pragma unroll
        for (int g = 0; g < 6; ++g) {
            f32x2 v  = *(const f32x2*)(const void*)&Gt[mm][g * 16 + kp];
            f32x2 bp = *(const f32x2*)(const void*)(Bp + g * 256 + k);
            gv[g] = useb ? (v + bp) : v;
        }

        f32x2 hro = *(const f32x2*)(const void*)(hfc + (size_t)n * KH_ + k);
        f32x2 hco = *(const f32x2*)(const void*)(hfc + (size_t)n * KH_ + 256 + k);

        f32x2 hrv, hcv;
#pragma unroll
        for (int j = 0; j < 2; ++j) {
            float ur = fsig(gv[0][j]);
            float oR = fsig(gv[1][j]);
            float uc = fsig(gv[2][j]);
            float oc = fsig(gv[3][j]);
            float ir = ftanhf(gv[4][j]);
            float ic = ftanhf(gv[5][j]);
            hrv[j] = ftanhf((1.f - ur) * hro[j] + ur * ir) * oR;
            hcv[j] = ftanhf((1.f - uc) * hco[j] + uc * ic) * oc;
        }

        // trace output (write-only: non-temporal, keep L2 clean for W/h)
        float* o0 = out0 + ((size_t)n * L_ + s) * 512;
        __builtin_nontemporal_store(hrv, (f32x2*)(void*)(o0 + k));
        __builtin_nontemporal_store(hcv, (f32x2*)(void*)(o0 + 256 + k));

        int n2 = n + B_; if (n2 >= N_) n2 -= N_;
        *(f32x2*)(void*)(hfn + (size_t)n  * KH_ + k)       = hrv;
        *(f32x2*)(void*)(hfn + (size_t)n2 * KH_ + 256 + k) = hcv;

        __hip_bfloat162 hr2, hc2;
        hr2.x = __float2bfloat16(hrv[0]); hr2.y = __float2bfloat16(hrv[1]);
        hc2.x = __float2bfloat16(hcv[0]); hc2.y = __float2bfloat16(hcv[1]);
        *(__hip_bfloat162*)(void*)(hbn + (size_t)n  * KH_ + k)       = hr2;
        *(__hip_bfloat162*)(void*)(hbn + (size_t)n2 * KH_ + 256 + k) = hc2;

        if (s >= LOR_ - 1 && r == s - (LOR_ - 1))
            __builtin_nontemporal_store(hrv, (f32x2*)(void*)(out2 + (size_t)(b * R_ + r) * H_ + k));
        if (r == R_ - 1 && s >= R_ - 1)
            __builtin_nontemporal_store(hcv, (f32x2*)(void*)(out1 + (size_t)(b * LOR_ + (s - (R_ - 1))) * H_ + k));
    }
}

// ---------------------------------------------------------------------------
extern "C" void kernel_launch(void* const* d_in, const int* in_sizes, int n_in,
                              void* d_out, int out_size, void* d_ws, size_t ws_size,
                              hipStream_t stream) {
    const float* inp = (const float*)d_in[0];
    const float* W   = (const float*)d_in[1];
    const float* Bp  = (const float*)d_in[2];

    float* out0 = (float*)d_out;
    float* out1 = out0 + (size_t)N_ * L_ * 512;
    float* out2 = out1 + (size_t)B_ * LOR_ * H_;

    char* ws = (char*)d_ws;
    __hip_bfloat16* Wfrag = (__hip_bfloat16*)(ws);                 // 3,342,336 B
    __hip_bfloat16* xall  = (__hip_bfloat16*)(ws + 3342336);       // 3,489,792 B
    __hip_bfloat16* hbf0  = (__hip_bfloat16*)(ws + 6832128);       //   786,432 B
    __hip_bfloat16* hbf1  = (__hip_bfloat16*)(ws + 7618560);       //   786,432 B
    float*          hf0   = (float*)(ws + 8404992);                // 1,572,864 B
    float*          hf1   = (float*)(ws + 9977856);                // 1,572,864 B

    (void)hipMemsetAsync(hbf0, 0, 786432, stream);
    (void)hipMemsetAsync(hf0,  0, 1572864, stream);

    prep_w<<<6528, 256, 0, stream>>>(W, Wfrag);
    prep_x<<<6816, 256, 0, stream>>>(inp, xall);

    for (int s = 0; s < L_; ++s) {
        const __hip_bfloat16* hbc = (s & 1) ? hbf1 : hbf0;
        __hip_bfloat16*       hbn = (s & 1) ? hbf0 : hbf1;
        const float*          hfc = (s & 1) ? hf1 : hf0;
        float*                hfn = (s & 1) ? hf0 : hf1;
        step_k<<<256, 384, 0, stream>>>(Wfrag, xall, hbc, hfc, hbn, hfn,
                                        Bp, out0, out1, out2, s);
    }
}